// Round 1
// baseline (1288.301 us; speedup 1.0000x reference)
//
#include <hip/hip_runtime.h>
#include <hip/hip_bf16.h>

typedef unsigned short u16;
typedef short s16x8 __attribute__((ext_vector_type(8)));
typedef u16 u16x4 __attribute__((ext_vector_type(4)));
typedef u16 u16x8 __attribute__((ext_vector_type(8)));
typedef float f32x4 __attribute__((ext_vector_type(4)));

__device__ __forceinline__ u16 f2bf(float f) {
    __hip_bfloat16 b = __float2bfloat16(f);
    return __builtin_bit_cast(u16, b);
}
__device__ __forceinline__ float bf2f(u16 u) {
    unsigned int x = ((unsigned int)u) << 16;
    return __builtin_bit_cast(float, x);
}

// ---------------- degree / norm / CSR build ----------------

__global__ void count_k(const int* __restrict__ src, const int* __restrict__ dst,
                        int* __restrict__ dout, int* __restrict__ din, int e) {
    int i = blockIdx.x * blockDim.x + threadIdx.x;
    if (i < e) {
        atomicAdd(&dout[src[i]], 1);
        atomicAdd(&din[dst[i]], 1);
    }
}

__global__ void norms_k(const int* __restrict__ dout, const int* __restrict__ din,
                        float* __restrict__ ns, float* __restrict__ nd, int n) {
    int i = blockIdx.x * blockDim.x + threadIdx.x;
    if (i < n) {
        ns[i] = 1.0f / sqrtf(fmaxf((float)dout[i], 1.0f));
        nd[i] = 1.0f / sqrtf(fmaxf((float)din[i], 1.0f));
    }
}

// per-block exclusive scan of 512 elems, block sums out
__global__ void scan1_k(const int* __restrict__ in, int* __restrict__ out,
                        int* __restrict__ sums, int n) {
    __shared__ int tmp[512];
    int t = threadIdx.x;
    int i = blockIdx.x * 512 + t;
    int v = (i < n) ? in[i] : 0;
    tmp[t] = v;
    __syncthreads();
    for (int d = 1; d < 512; d <<= 1) {
        int add = (t >= d) ? tmp[t - d] : 0;
        __syncthreads();
        tmp[t] += add;
        __syncthreads();
    }
    if (i < n) out[i] = tmp[t] - v;  // exclusive within chunk
    if (t == 511) sums[blockIdx.x] = tmp[511];
}

__global__ void scan2_k(const int* __restrict__ sums, int* __restrict__ offs, int nb) {
    __shared__ int tmp[256];
    int t = threadIdx.x;
    int v = (t < nb) ? sums[t] : 0;
    tmp[t] = v;
    __syncthreads();
    for (int d = 1; d < 256; d <<= 1) {
        int add = (t >= d) ? tmp[t - d] : 0;
        __syncthreads();
        tmp[t] += add;
        __syncthreads();
    }
    if (t < nb) offs[t] = tmp[t] - v;
}

__global__ void scan3_k(int* __restrict__ rp, const int* __restrict__ offs,
                        int* __restrict__ cur, int n, int E) {
    int i = blockIdx.x * blockDim.x + threadIdx.x;
    if (i < n) {
        int v = rp[i] + offs[i >> 9];
        rp[i] = v;
        cur[i] = v;
    } else if (i == n) {
        rp[n] = E;
    }
}

__global__ void fill_k(const int* __restrict__ src, const int* __restrict__ dst,
                       int* __restrict__ cur, int* __restrict__ col, int e) {
    int i = blockIdx.x * blockDim.x + threadIdx.x;
    if (i < e) {
        int p = atomicAdd(&cur[dst[i]], 1);
        col[p] = src[i];
    }
}

// transpose-convert W[k][n] (f32) -> Wt[n][k] (bf16)
__global__ void convt_k(const float* __restrict__ W, u16* __restrict__ Wt, int K, int Nn) {
    int i = blockIdx.x * blockDim.x + threadIdx.x;
    if (i < K * Nn) {
        int n = i / K, k = i - n * K;
        Wt[i] = f2bf(W[(size_t)k * Nn + n]);
    }
}

// ---------------- GEMM: C[M][256] = A(scaled,bf16) @ W, tile 128x128x64 ----------------

template <int K, bool AF32>
__global__ __launch_bounds__(256) void gemm_k(const void* __restrict__ Ap,
                                              const float* __restrict__ nsrc,
                                              const u16* __restrict__ Bt,  // [256][K] bf16 (W^T)
                                              u16* __restrict__ C, int M) {
    constexpr int BMt = 128, BKt = 64;
    __shared__ u16 Al[BMt * BKt];
    __shared__ u16 Bl[128 * BKt];
    const int tid = threadIdx.x, lane = tid & 63, wid = tid >> 6;
    const int wr = wid >> 1, wc = wid & 1;
    const int l15 = lane & 15, lhi = lane >> 4;
    const int bm = blockIdx.x * BMt, bn = blockIdx.y * 128;
    f32x4 acc[4][4] = {};

    for (int k0 = 0; k0 < K; k0 += BKt) {
        // stage A and B tiles: 1024 granules of 16B each, 4 per thread
#pragma unroll
        for (int i = 0; i < 4; i++) {
            int G = i * 256 + tid, row = G >> 3, gk = G & 7;
            int grow = bm + row;
            grow = grow < M ? grow : M - 1;
            u16x8 w;
            if constexpr (AF32) {
                const float* A = (const float*)Ap;
                const f32x4 v0 = *(const f32x4*)(A + (size_t)grow * K + k0 + gk * 8);
                const f32x4 v1 = *(const f32x4*)(A + (size_t)grow * K + k0 + gk * 8 + 4);
                const float ns = nsrc[grow];
                w[0] = f2bf(v0[0] * ns); w[1] = f2bf(v0[1] * ns);
                w[2] = f2bf(v0[2] * ns); w[3] = f2bf(v0[3] * ns);
                w[4] = f2bf(v1[0] * ns); w[5] = f2bf(v1[1] * ns);
                w[6] = f2bf(v1[2] * ns); w[7] = f2bf(v1[3] * ns);
            } else {
                const u16* A = (const u16*)Ap;
                w = *(const u16x8*)(A + (size_t)grow * K + k0 + gk * 8);
            }
            int idx = (row * BKt + gk * 8) ^ ((row & 7) << 3);  // XOR swizzle, 16B granules
            *(u16x8*)(Al + idx) = w;
            // B tile: rows are output cols n = bn+row, always < 256
            u16x8 wb = *(const u16x8*)(Bt + (size_t)(bn + row) * K + k0 + gk * 8);
            *(u16x8*)(Bl + idx) = wb;
        }
        __syncthreads();

        s16x8 af[2][4], bfr[2][4];
#pragma unroll
        for (int kk = 0; kk < 2; kk++) {
#pragma unroll
            for (int mi = 0; mi < 4; mi++) {
                int row = wr * 64 + mi * 16 + l15;
                int idx = (row * BKt + kk * 32 + lhi * 8) ^ ((row & 7) << 3);
                af[kk][mi] = *(const s16x8*)(Al + idx);
            }
#pragma unroll
            for (int ni = 0; ni < 4; ni++) {
                int n = wc * 64 + ni * 16 + l15;
                int idx = (n * BKt + kk * 32 + lhi * 8) ^ ((n & 7) << 3);
                bfr[kk][ni] = *(const s16x8*)(Bl + idx);
            }
        }
#pragma unroll
        for (int kk = 0; kk < 2; kk++)
#pragma unroll
            for (int mi = 0; mi < 4; mi++)
#pragma unroll
                for (int ni = 0; ni < 4; ni++)
                    acc[mi][ni] = __builtin_amdgcn_mfma_f32_16x16x32_bf16(
                        af[kk][mi], bfr[kk][ni], acc[mi][ni], 0, 0, 0);
        __syncthreads();
    }

    // epilogue: C/D layout col=lane&15, row=(lane>>4)*4+reg
#pragma unroll
    for (int mi = 0; mi < 4; mi++) {
#pragma unroll
        for (int r = 0; r < 4; r++) {
            int grow = bm + wr * 64 + mi * 16 + lhi * 4 + r;
            if (grow < M) {
#pragma unroll
                for (int ni = 0; ni < 4; ni++) {
                    int gcol = bn + wc * 64 + ni * 16 + l15;
                    C[(size_t)grow * 256 + gcol] = f2bf(acc[mi][ni][r]);
                }
            }
        }
    }
}

// ---------------- pull aggregation + epilogue (norm_dst, bias, PReLU, [norm_src->bf16]) ----

__global__ __launch_bounds__(256) void agg_k(const u16* __restrict__ h,
                                             const int* __restrict__ rp,
                                             const int* __restrict__ col,
                                             const float* __restrict__ nd,
                                             const float* __restrict__ bias,
                                             const float* __restrict__ alpha,
                                             const float* __restrict__ ns,
                                             u16* __restrict__ obf, float* __restrict__ of,
                                             int n) {
    int w = (blockIdx.x * blockDim.x + threadIdx.x) >> 6;
    if (w >= n) return;
    const int lane = threadIdx.x & 63, c0 = lane * 4;
    const int beg = rp[w], end = rp[w + 1];
    float s0 = 0.f, s1 = 0.f, s2 = 0.f, s3 = 0.f;
    for (int e = beg; e < end; e++) {
        int sN = col[e];
        u16x4 v = *(const u16x4*)(h + (size_t)sN * 256 + c0);
        s0 += bf2f(v[0]); s1 += bf2f(v[1]); s2 += bf2f(v[2]); s3 += bf2f(v[3]);
    }
    const float ndv = nd[w];
    const f32x4 b = *(const f32x4*)(bias + c0);
    const f32x4 al = *(const f32x4*)(alpha + c0);
    s0 = s0 * ndv + b[0]; s1 = s1 * ndv + b[1];
    s2 = s2 * ndv + b[2]; s3 = s3 * ndv + b[3];
    s0 = s0 > 0.f ? s0 : al[0] * s0;
    s1 = s1 > 0.f ? s1 : al[1] * s1;
    s2 = s2 > 0.f ? s2 : al[2] * s2;
    s3 = s3 > 0.f ? s3 : al[3] * s3;
    if (obf) {
        const float nsv = ns[w];
        u16x4 o;
        o[0] = f2bf(s0 * nsv); o[1] = f2bf(s1 * nsv);
        o[2] = f2bf(s2 * nsv); o[3] = f2bf(s3 * nsv);
        *(u16x4*)(obf + (size_t)w * 256 + c0) = o;
    } else {
        f32x4 o;
        o[0] = s0; o[1] = s1; o[2] = s2; o[3] = s3;
        *(f32x4*)(of + (size_t)w * 256 + c0) = o;
    }
}

// ---------------- launch ----------------

extern "C" void kernel_launch(void* const* d_in, const int* in_sizes, int n_in,
                              void* d_out, int out_size, void* d_ws, size_t ws_size,
                              hipStream_t stream) {
    const float* feat = (const float*)d_in[0];
    const int* src = (const int*)d_in[1];
    const int* dst = (const int*)d_in[2];
    const float* W1 = (const float*)d_in[3];
    const float* b1 = (const float*)d_in[4];
    const float* a1 = (const float*)d_in[5];
    const float* W2 = (const float*)d_in[6];
    const float* b2 = (const float*)d_in[7];
    const float* a2 = (const float*)d_in[8];
    float* out = (float*)d_out;

    const int N = in_sizes[0] / 512;  // 100000
    const int E = in_sizes[1];        // 3200000

    char* ws = (char*)d_ws;
    size_t off = 0;
    auto take = [&](size_t bytes) {
        size_t o = off;
        off += (bytes + 255) & ~(size_t)255;
        return o;
    };
    int* deg_out = (int*)(ws + take((size_t)N * 4));
    int* deg_in = (int*)(ws + take((size_t)N * 4));
    float* nsrc = (float*)(ws + take((size_t)N * 4));
    float* ndst = (float*)(ws + take((size_t)N * 4));
    int* row_ptr = (int*)(ws + take((size_t)(N + 1) * 4));
    int* row_cur = (int*)(ws + take((size_t)N * 4));
    int* sums = (int*)(ws + take(1024));
    int* offs = (int*)(ws + take(1024));
    int* col = (int*)(ws + take((size_t)E * 4));
    u16* W1t = (u16*)(ws + take((size_t)512 * 256 * 2));
    u16* W2t = (u16*)(ws + take((size_t)256 * 256 * 2));
    u16* h = (u16*)(ws + take((size_t)N * 256 * 2));
    u16* x2 = (u16*)(ws + take((size_t)N * 256 * 2));

    hipMemsetAsync(deg_out, 0, (size_t)N * 4, stream);
    hipMemsetAsync(deg_in, 0, (size_t)N * 4, stream);

    count_k<<<(E + 255) / 256, 256, 0, stream>>>(src, dst, deg_out, deg_in, E);
    norms_k<<<(N + 255) / 256, 256, 0, stream>>>(deg_out, deg_in, nsrc, ndst, N);

    int nb = (N + 511) / 512;  // 196
    scan1_k<<<nb, 512, 0, stream>>>(deg_in, row_ptr, sums, N);
    scan2_k<<<1, 256, 0, stream>>>(sums, offs, nb);
    scan3_k<<<(N + 1 + 255) / 256, 256, 0, stream>>>(row_ptr, offs, row_cur, N, E);
    fill_k<<<(E + 255) / 256, 256, 0, stream>>>(src, dst, row_cur, col, E);

    convt_k<<<(512 * 256 + 255) / 256, 256, 0, stream>>>(W1, W1t, 512, 256);
    convt_k<<<(256 * 256 + 255) / 256, 256, 0, stream>>>(W2, W2t, 256, 256);

    dim3 gg((N + 127) / 128, 2);
    int aggBlocks = (N * 64 + 255) / 256;

    // layer 1
    gemm_k<512, true><<<gg, 256, 0, stream>>>(feat, nsrc, W1t, h, N);
    agg_k<<<aggBlocks, 256, 0, stream>>>(h, row_ptr, col, ndst, b1, a1, nsrc, x2, nullptr, N);
    // layer 2
    gemm_k<256, false><<<gg, 256, 0, stream>>>(x2, nullptr, W2t, h, N);
    agg_k<<<aggBlocks, 256, 0, stream>>>(h, row_ptr, col, ndst, b2, a2, nullptr, nullptr, out, N);
}

// Round 2
// 1068.608 us; speedup vs baseline: 1.2056x; 1.2056x over previous
//
#include <hip/hip_runtime.h>
#include <hip/hip_bf16.h>

typedef unsigned short u16;
typedef short s16x8 __attribute__((ext_vector_type(8)));
typedef u16 u16x4 __attribute__((ext_vector_type(4)));
typedef u16 u16x8 __attribute__((ext_vector_type(8)));
typedef float f32x4 __attribute__((ext_vector_type(4)));

__device__ __forceinline__ u16 f2bf(float f) {
    __hip_bfloat16 b = __float2bfloat16(f);
    return __builtin_bit_cast(u16, b);
}
__device__ __forceinline__ float bf2f(u16 u) {
    unsigned int x = ((unsigned int)u) << 16;
    return __builtin_bit_cast(float, x);
}

// ---------------- degree / norm / CSR build ----------------

__global__ void count_k(const int* __restrict__ src, const int* __restrict__ dst,
                        int* __restrict__ dout, int* __restrict__ din, int e) {
    int i = blockIdx.x * blockDim.x + threadIdx.x;
    if (i < e) {
        atomicAdd(&dout[src[i]], 1);
        atomicAdd(&din[dst[i]], 1);
    }
}

__global__ void norms_k(const int* __restrict__ dout, const int* __restrict__ din,
                        float* __restrict__ ns, float* __restrict__ nd, int n) {
    int i = blockIdx.x * blockDim.x + threadIdx.x;
    if (i < n) {
        ns[i] = 1.0f / sqrtf(fmaxf((float)dout[i], 1.0f));
        nd[i] = 1.0f / sqrtf(fmaxf((float)din[i], 1.0f));
    }
}

// per-block exclusive scan of 512 elems, block sums out
__global__ void scan1_k(const int* __restrict__ in, int* __restrict__ out,
                        int* __restrict__ sums, int n) {
    __shared__ int tmp[512];
    int t = threadIdx.x;
    int i = blockIdx.x * 512 + t;
    int v = (i < n) ? in[i] : 0;
    tmp[t] = v;
    __syncthreads();
    for (int d = 1; d < 512; d <<= 1) {
        int add = (t >= d) ? tmp[t - d] : 0;
        __syncthreads();
        tmp[t] += add;
        __syncthreads();
    }
    if (i < n) out[i] = tmp[t] - v;  // exclusive within chunk
    if (t == 511) sums[blockIdx.x] = tmp[511];
}

__global__ void scan2_k(const int* __restrict__ sums, int* __restrict__ offs, int nb) {
    __shared__ int tmp[256];
    int t = threadIdx.x;
    int v = (t < nb) ? sums[t] : 0;
    tmp[t] = v;
    __syncthreads();
    for (int d = 1; d < 256; d <<= 1) {
        int add = (t >= d) ? tmp[t - d] : 0;
        __syncthreads();
        tmp[t] += add;
        __syncthreads();
    }
    if (t < nb) offs[t] = tmp[t] - v;
}

__global__ void scan3_k(int* __restrict__ rp, const int* __restrict__ offs,
                        int* __restrict__ cur, int n, int E) {
    int i = blockIdx.x * blockDim.x + threadIdx.x;
    if (i < n) {
        int v = rp[i] + offs[i >> 9];
        rp[i] = v;
        cur[i] = v;
    } else if (i == n) {
        rp[n] = E;
    }
}

__global__ void fill_k(const int* __restrict__ src, const int* __restrict__ dst,
                       int* __restrict__ cur, int* __restrict__ col, int e) {
    int i = blockIdx.x * blockDim.x + threadIdx.x;
    if (i < e) {
        int p = atomicAdd(&cur[dst[i]], 1);
        col[p] = src[i];
    }
}

// transpose-convert W[k][n] (f32) -> Wt[n][k] (bf16)
__global__ void convt_k(const float* __restrict__ W, u16* __restrict__ Wt, int K, int Nn) {
    int i = blockIdx.x * blockDim.x + threadIdx.x;
    if (i < K * Nn) {
        int n = i / K, k = i - n * K;
        Wt[i] = f2bf(W[(size_t)k * Nn + n]);
    }
}

// ---------------- GEMM: C[M][256] = A(scaled,bf16) @ W, tile 128x128x64 ----------------

template <int K, bool AF32>
__global__ __launch_bounds__(256) void gemm_k(const void* __restrict__ Ap,
                                              const float* __restrict__ nsrc,
                                              const u16* __restrict__ Bt,  // [256][K] bf16 (W^T)
                                              u16* __restrict__ C, int M) {
    constexpr int BMt = 128, BKt = 64;
    __shared__ u16 Al[BMt * BKt];
    __shared__ u16 Bl[128 * BKt];
    const int tid = threadIdx.x, lane = tid & 63, wid = tid >> 6;
    const int wr = wid >> 1, wc = wid & 1;
    const int l15 = lane & 15, lhi = lane >> 4;
    const int bm = blockIdx.x * BMt, bn = blockIdx.y * 128;
    f32x4 acc[4][4] = {};

    for (int k0 = 0; k0 < K; k0 += BKt) {
        // stage A and B tiles: 1024 granules of 16B each, 4 per thread
#pragma unroll
        for (int i = 0; i < 4; i++) {
            int G = i * 256 + tid, row = G >> 3, gk = G & 7;
            int grow = bm + row;
            grow = grow < M ? grow : M - 1;
            u16x8 w;
            if constexpr (AF32) {
                const float* A = (const float*)Ap;
                const f32x4 v0 = *(const f32x4*)(A + (size_t)grow * K + k0 + gk * 8);
                const f32x4 v1 = *(const f32x4*)(A + (size_t)grow * K + k0 + gk * 8 + 4);
                const float ns = nsrc[grow];
                w[0] = f2bf(v0[0] * ns); w[1] = f2bf(v0[1] * ns);
                w[2] = f2bf(v0[2] * ns); w[3] = f2bf(v0[3] * ns);
                w[4] = f2bf(v1[0] * ns); w[5] = f2bf(v1[1] * ns);
                w[6] = f2bf(v1[2] * ns); w[7] = f2bf(v1[3] * ns);
            } else {
                const u16* A = (const u16*)Ap;
                w = *(const u16x8*)(A + (size_t)grow * K + k0 + gk * 8);
            }
            int idx = (row * BKt + gk * 8) ^ ((row & 7) << 3);  // XOR swizzle, 16B granules
            *(u16x8*)(Al + idx) = w;
            // B tile: rows are output cols n = bn+row, always < 256
            u16x8 wb = *(const u16x8*)(Bt + (size_t)(bn + row) * K + k0 + gk * 8);
            *(u16x8*)(Bl + idx) = wb;
        }
        __syncthreads();

        s16x8 af[2][4], bfr[2][4];
#pragma unroll
        for (int kk = 0; kk < 2; kk++) {
#pragma unroll
            for (int mi = 0; mi < 4; mi++) {
                int row = wr * 64 + mi * 16 + l15;
                int idx = (row * BKt + kk * 32 + lhi * 8) ^ ((row & 7) << 3);
                af[kk][mi] = *(const s16x8*)(Al + idx);
            }
#pragma unroll
            for (int ni = 0; ni < 4; ni++) {
                int n = wc * 64 + ni * 16 + l15;
                int idx = (n * BKt + kk * 32 + lhi * 8) ^ ((n & 7) << 3);
                bfr[kk][ni] = *(const s16x8*)(Bl + idx);
            }
        }
#pragma unroll
        for (int kk = 0; kk < 2; kk++)
#pragma unroll
            for (int mi = 0; mi < 4; mi++)
#pragma unroll
                for (int ni = 0; ni < 4; ni++)
                    acc[mi][ni] = __builtin_amdgcn_mfma_f32_16x16x32_bf16(
                        af[kk][mi], bfr[kk][ni], acc[mi][ni], 0, 0, 0);
        __syncthreads();
    }

    // epilogue: C/D layout col=lane&15, row=(lane>>4)*4+reg
#pragma unroll
    for (int mi = 0; mi < 4; mi++) {
#pragma unroll
        for (int r = 0; r < 4; r++) {
            int grow = bm + wr * 64 + mi * 16 + lhi * 4 + r;
            if (grow < M) {
#pragma unroll
                for (int ni = 0; ni < 4; ni++) {
                    int gcol = bn + wc * 64 + ni * 16 + l15;
                    C[(size_t)grow * 256 + gcol] = f2bf(acc[mi][ni][r]);
                }
            }
        }
    }
}

// ---------------- pull aggregation + epilogue (norm_dst, bias, PReLU, [norm_src->bf16]) ----
// One wave per dst node. 16B/lane: 32 lanes cover a 256ch bf16 row, so the wave
// processes 2 edges per gather; manual 2x unroll => 4 edges (2KB) in flight.

__global__ __launch_bounds__(256) void agg_k(const u16* __restrict__ h,
                                             const int* __restrict__ rp,
                                             const int* __restrict__ col,
                                             const float* __restrict__ nd,
                                             const float* __restrict__ bias,
                                             const float* __restrict__ alpha,
                                             const float* __restrict__ ns,
                                             u16* __restrict__ obf, float* __restrict__ of,
                                             int n) {
    int w = (blockIdx.x * blockDim.x + threadIdx.x) >> 6;
    if (w >= n) return;
    const int lane = threadIdx.x & 63;
    const int half = lane >> 5, l32 = lane & 31, c0 = l32 * 8;
    const int beg = rp[w], end = rp[w + 1];

    float a[8] = {0.f, 0.f, 0.f, 0.f, 0.f, 0.f, 0.f, 0.f};
    float b[8] = {0.f, 0.f, 0.f, 0.f, 0.f, 0.f, 0.f, 0.f};

    int p = beg + half;  // lanes 0-31 take even slots, 32-63 odd slots
    for (; p + 2 < end; p += 4) {
        int s1 = col[p];
        int s2 = col[p + 2];
        u16x8 v1 = *(const u16x8*)(h + (size_t)s1 * 256 + c0);
        u16x8 v2 = *(const u16x8*)(h + (size_t)s2 * 256 + c0);
#pragma unroll
        for (int j = 0; j < 8; j++) {
            a[j] += bf2f(v1[j]);
            b[j] += bf2f(v2[j]);
        }
    }
    if (p < end) {
        int s1 = col[p];
        u16x8 v1 = *(const u16x8*)(h + (size_t)s1 * 256 + c0);
#pragma unroll
        for (int j = 0; j < 8; j++) a[j] += bf2f(v1[j]);
    }
#pragma unroll
    for (int j = 0; j < 8; j++) a[j] += b[j];
    // combine the two half-wave partial sums (channels identical across halves)
#pragma unroll
    for (int j = 0; j < 8; j++) a[j] += __shfl_xor(a[j], 32);

    const float ndv = nd[w];
    const f32x4 bv0 = *(const f32x4*)(bias + c0);
    const f32x4 bv1 = *(const f32x4*)(bias + c0 + 4);
    const f32x4 al0 = *(const f32x4*)(alpha + c0);
    const f32x4 al1 = *(const f32x4*)(alpha + c0 + 4);
    float bb[8] = {bv0[0], bv0[1], bv0[2], bv0[3], bv1[0], bv1[1], bv1[2], bv1[3]};
    float aa[8] = {al0[0], al0[1], al0[2], al0[3], al1[0], al1[1], al1[2], al1[3]};
#pragma unroll
    for (int j = 0; j < 8; j++) {
        float s = a[j] * ndv + bb[j];
        a[j] = s > 0.f ? s : aa[j] * s;
    }

    if (half == 0) {
        if (obf) {
            const float nsv = ns[w];
            u16x8 o;
#pragma unroll
            for (int j = 0; j < 8; j++) o[j] = f2bf(a[j] * nsv);
            *(u16x8*)(obf + (size_t)w * 256 + c0) = o;
        } else {
            f32x4 o0, o1;
            o0[0] = a[0]; o0[1] = a[1]; o0[2] = a[2]; o0[3] = a[3];
            o1[0] = a[4]; o1[1] = a[5]; o1[2] = a[6]; o1[3] = a[7];
            *(f32x4*)(of + (size_t)w * 256 + c0) = o0;
            *(f32x4*)(of + (size_t)w * 256 + c0 + 4) = o1;
        }
    }
}

// ---------------- launch ----------------

extern "C" void kernel_launch(void* const* d_in, const int* in_sizes, int n_in,
                              void* d_out, int out_size, void* d_ws, size_t ws_size,
                              hipStream_t stream) {
    const float* feat = (const float*)d_in[0];
    const int* src = (const int*)d_in[1];
    const int* dst = (const int*)d_in[2];
    const float* W1 = (const float*)d_in[3];
    const float* b1 = (const float*)d_in[4];
    const float* a1 = (const float*)d_in[5];
    const float* W2 = (const float*)d_in[6];
    const float* b2 = (const float*)d_in[7];
    const float* a2 = (const float*)d_in[8];
    float* out = (float*)d_out;

    const int N = in_sizes[0] / 512;  // 100000
    const int E = in_sizes[1];        // 3200000

    char* ws = (char*)d_ws;
    size_t off = 0;
    auto take = [&](size_t bytes) {
        size_t o = off;
        off += (bytes + 255) & ~(size_t)255;
        return o;
    };
    int* deg_out = (int*)(ws + take((size_t)N * 4));
    int* deg_in = (int*)(ws + take((size_t)N * 4));
    float* nsrc = (float*)(ws + take((size_t)N * 4));
    float* ndst = (float*)(ws + take((size_t)N * 4));
    int* row_ptr = (int*)(ws + take((size_t)(N + 1) * 4));
    int* row_cur = (int*)(ws + take((size_t)N * 4));
    int* sums = (int*)(ws + take(1024));
    int* offs = (int*)(ws + take(1024));
    int* col = (int*)(ws + take((size_t)E * 4));
    u16* W1t = (u16*)(ws + take((size_t)512 * 256 * 2));
    u16* W2t = (u16*)(ws + take((size_t)256 * 256 * 2));
    u16* h = (u16*)(ws + take((size_t)N * 256 * 2));
    u16* x2 = (u16*)(ws + take((size_t)N * 256 * 2));

    hipMemsetAsync(deg_out, 0, (size_t)N * 4, stream);
    hipMemsetAsync(deg_in, 0, (size_t)N * 4, stream);

    count_k<<<(E + 255) / 256, 256, 0, stream>>>(src, dst, deg_out, deg_in, E);
    norms_k<<<(N + 255) / 256, 256, 0, stream>>>(deg_out, deg_in, nsrc, ndst, N);

    int nb = (N + 511) / 512;  // 196
    scan1_k<<<nb, 512, 0, stream>>>(deg_in, row_ptr, sums, N);
    scan2_k<<<1, 256, 0, stream>>>(sums, offs, nb);
    scan3_k<<<(N + 1 + 255) / 256, 256, 0, stream>>>(row_ptr, offs, row_cur, N, E);
    fill_k<<<(E + 255) / 256, 256, 0, stream>>>(src, dst, row_cur, col, E);

    convt_k<<<(512 * 256 + 255) / 256, 256, 0, stream>>>(W1, W1t, 512, 256);
    convt_k<<<(256 * 256 + 255) / 256, 256, 0, stream>>>(W2, W2t, 256, 256);

    dim3 gg((N + 127) / 128, 2);
    int aggBlocks = (N * 64 + 255) / 256;

    // layer 1
    gemm_k<512, true><<<gg, 256, 0, stream>>>(feat, nsrc, W1t, h, N);
    agg_k<<<aggBlocks, 256, 0, stream>>>(h, row_ptr, col, ndst, b1, a1, nsrc, x2, nullptr, N);
    // layer 2
    gemm_k<256, false><<<gg, 256, 0, stream>>>(x2, nullptr, W2t, h, N);
    agg_k<<<aggBlocks, 256, 0, stream>>>(h, row_ptr, col, ndst, b2, a2, nullptr, nullptr, out, N);
}

// Round 3
// 955.739 us; speedup vs baseline: 1.3480x; 1.1181x over previous
//
#include <hip/hip_runtime.h>
#include <hip/hip_bf16.h>

typedef unsigned short u16;
typedef short s16x8 __attribute__((ext_vector_type(8)));
typedef u16 u16x4 __attribute__((ext_vector_type(4)));
typedef u16 u16x8 __attribute__((ext_vector_type(8)));
typedef float f32x4 __attribute__((ext_vector_type(4)));

#define BSHIFT 10  // bucket = dst >> 10 (1024 nodes per bucket)

__device__ __forceinline__ u16 f2bf(float f) {
    __hip_bfloat16 b = __float2bfloat16(f);
    return __builtin_bit_cast(u16, b);
}
__device__ __forceinline__ float bf2f(u16 u) {
    unsigned int x = ((unsigned int)u) << 16;
    return __builtin_bit_cast(float, x);
}

// ---------------- degree / norm ----------------

__global__ void count_k(const int* __restrict__ src, const int* __restrict__ dst,
                        int* __restrict__ dout, int* __restrict__ din, int e) {
    int i = blockIdx.x * blockDim.x + threadIdx.x;
    if (i < e) {
        atomicAdd(&dout[src[i]], 1);
        atomicAdd(&din[dst[i]], 1);
    }
}

__global__ void norms_k(const int* __restrict__ dout, const int* __restrict__ din,
                        float* __restrict__ ns, float* __restrict__ nd, int n) {
    int i = blockIdx.x * blockDim.x + threadIdx.x;
    if (i < n) {
        ns[i] = 1.0f / sqrtf(fmaxf((float)dout[i], 1.0f));
        nd[i] = 1.0f / sqrtf(fmaxf((float)din[i], 1.0f));
    }
}

// per-block exclusive scan of 512 elems, block sums out
__global__ void scan1_k(const int* __restrict__ in, int* __restrict__ out,
                        int* __restrict__ sums, int n) {
    __shared__ int tmp[512];
    int t = threadIdx.x;
    int i = blockIdx.x * 512 + t;
    int v = (i < n) ? in[i] : 0;
    tmp[t] = v;
    __syncthreads();
    for (int d = 1; d < 512; d <<= 1) {
        int add = (t >= d) ? tmp[t - d] : 0;
        __syncthreads();
        tmp[t] += add;
        __syncthreads();
    }
    if (i < n) out[i] = tmp[t] - v;  // exclusive within chunk
    if (t == 511) sums[blockIdx.x] = tmp[511];
}

__global__ void scan2_k(const int* __restrict__ sums, int* __restrict__ offs, int nb) {
    __shared__ int tmp[256];
    int t = threadIdx.x;
    int v = (t < nb) ? sums[t] : 0;
    tmp[t] = v;
    __syncthreads();
    for (int d = 1; d < 256; d <<= 1) {
        int add = (t >= d) ? tmp[t - d] : 0;
        __syncthreads();
        tmp[t] += add;
        __syncthreads();
    }
    if (t < nb) offs[t] = tmp[t] - v;
}

__global__ void scan3_k(int* __restrict__ rp, const int* __restrict__ offs,
                        int* __restrict__ cur, int n, int E) {
    int i = blockIdx.x * blockDim.x + threadIdx.x;
    if (i < n) {
        int v = rp[i] + offs[i >> 9];
        rp[i] = v;
        cur[i] = v;
    } else if (i == n) {
        rp[n] = E;
    }
}

// ---------------- bucketed CSR fill (low write-amplification) ----------------

__global__ void bcur_init_k(const int* __restrict__ rp, int* __restrict__ bcur,
                            int NB, int N) {
    int b = blockIdx.x * blockDim.x + threadIdx.x;
    if (b < NB) {
        int idx = b << BSHIFT;
        bcur[b] = rp[idx < N ? idx : N];
    }
}

// partition edges into dst-buckets: dense pair writes, 1 global atomic per (block,bucket)
__global__ __launch_bounds__(256) void partition_k(const int* __restrict__ src,
                                                   const int* __restrict__ dst,
                                                   int* __restrict__ bcur,
                                                   int2* __restrict__ pairs,
                                                   int E, int NB, int chunk) {
    __shared__ int hist[2048];
    const int base_e = blockIdx.x * chunk;
    const int end_e = (base_e + chunk) < E ? (base_e + chunk) : E;
    for (int b = threadIdx.x; b < NB; b += 256) hist[b] = 0;
    __syncthreads();
    for (int i = base_e + threadIdx.x; i < end_e; i += 256)
        atomicAdd(&hist[dst[i] >> BSHIFT], 1);
    __syncthreads();
    for (int b = threadIdx.x; b < NB; b += 256) {
        int c = hist[b];
        hist[b] = c ? atomicAdd(&bcur[b], c) : 0;
    }
    __syncthreads();
    for (int i = base_e + threadIdx.x; i < end_e; i += 256) {
        int d = dst[i], s = src[i];
        int pos = atomicAdd(&hist[d >> BSHIFT], 1);
        int2 pr; pr.x = s; pr.y = d;
        pairs[pos] = pr;
    }
}

// fine fill within buckets: atomics/writes now hit small L2-resident windows
__global__ void fill2_k(const int2* __restrict__ pairs, int* __restrict__ cur,
                        int* __restrict__ col, int e) {
    int i = blockIdx.x * blockDim.x + threadIdx.x;
    if (i < e) {
        int2 p = pairs[i];
        int pos = atomicAdd(&cur[p.y], 1);
        col[pos] = p.x;
    }
}

// transpose-convert W[k][n] (f32) -> Wt[n][k] (bf16)
__global__ void convt_k(const float* __restrict__ W, u16* __restrict__ Wt, int K, int Nn) {
    int i = blockIdx.x * blockDim.x + threadIdx.x;
    if (i < K * Nn) {
        int n = i / K, k = i - n * K;
        Wt[i] = f2bf(W[(size_t)k * Nn + n]);
    }
}

// ---------------- GEMM: C[M][256] = A(scaled,bf16) @ W, tile 128x128x64 ----------------

template <int K, bool AF32>
__global__ __launch_bounds__(256) void gemm_k(const void* __restrict__ Ap,
                                              const float* __restrict__ nsrc,
                                              const u16* __restrict__ Bt,  // [256][K] bf16 (W^T)
                                              u16* __restrict__ C, int M) {
    constexpr int BMt = 128, BKt = 64;
    __shared__ u16 Al[BMt * BKt];
    __shared__ u16 Bl[128 * BKt];
    const int tid = threadIdx.x, lane = tid & 63, wid = tid >> 6;
    const int wr = wid >> 1, wc = wid & 1;
    const int l15 = lane & 15, lhi = lane >> 4;
    const int bm = blockIdx.x * BMt, bn = blockIdx.y * 128;
    f32x4 acc[4][4] = {};

    for (int k0 = 0; k0 < K; k0 += BKt) {
#pragma unroll
        for (int i = 0; i < 4; i++) {
            int G = i * 256 + tid, row = G >> 3, gk = G & 7;
            int grow = bm + row;
            grow = grow < M ? grow : M - 1;
            u16x8 w;
            if constexpr (AF32) {
                const float* A = (const float*)Ap;
                const f32x4 v0 = *(const f32x4*)(A + (size_t)grow * K + k0 + gk * 8);
                const f32x4 v1 = *(const f32x4*)(A + (size_t)grow * K + k0 + gk * 8 + 4);
                const float ns = nsrc[grow];
                w[0] = f2bf(v0[0] * ns); w[1] = f2bf(v0[1] * ns);
                w[2] = f2bf(v0[2] * ns); w[3] = f2bf(v0[3] * ns);
                w[4] = f2bf(v1[0] * ns); w[5] = f2bf(v1[1] * ns);
                w[6] = f2bf(v1[2] * ns); w[7] = f2bf(v1[3] * ns);
            } else {
                const u16* A = (const u16*)Ap;
                w = *(const u16x8*)(A + (size_t)grow * K + k0 + gk * 8);
            }
            int idx = (row * BKt + gk * 8) ^ ((row & 7) << 3);  // XOR swizzle, 16B granules
            *(u16x8*)(Al + idx) = w;
            u16x8 wb = *(const u16x8*)(Bt + (size_t)(bn + row) * K + k0 + gk * 8);
            *(u16x8*)(Bl + idx) = wb;
        }
        __syncthreads();

        s16x8 af[2][4], bfr[2][4];
#pragma unroll
        for (int kk = 0; kk < 2; kk++) {
#pragma unroll
            for (int mi = 0; mi < 4; mi++) {
                int row = wr * 64 + mi * 16 + l15;
                int idx = (row * BKt + kk * 32 + lhi * 8) ^ ((row & 7) << 3);
                af[kk][mi] = *(const s16x8*)(Al + idx);
            }
#pragma unroll
            for (int ni = 0; ni < 4; ni++) {
                int n = wc * 64 + ni * 16 + l15;
                int idx = (n * BKt + kk * 32 + lhi * 8) ^ ((n & 7) << 3);
                bfr[kk][ni] = *(const s16x8*)(Bl + idx);
            }
        }
#pragma unroll
        for (int kk = 0; kk < 2; kk++)
#pragma unroll
            for (int mi = 0; mi < 4; mi++)
#pragma unroll
                for (int ni = 0; ni < 4; ni++)
                    acc[mi][ni] = __builtin_amdgcn_mfma_f32_16x16x32_bf16(
                        af[kk][mi], bfr[kk][ni], acc[mi][ni], 0, 0, 0);
        __syncthreads();
    }

    // epilogue: C/D layout col=lane&15, row=(lane>>4)*4+reg
#pragma unroll
    for (int mi = 0; mi < 4; mi++) {
#pragma unroll
        for (int r = 0; r < 4; r++) {
            int grow = bm + wr * 64 + mi * 16 + lhi * 4 + r;
            if (grow < M) {
#pragma unroll
                for (int ni = 0; ni < 4; ni++) {
                    int gcol = bn + wc * 64 + ni * 16 + l15;
                    C[(size_t)grow * 256 + gcol] = f2bf(acc[mi][ni][r]);
                }
            }
        }
    }
}

// ---------------- pull aggregation + epilogue ----------------
// One wave per dst node. 16B/lane, 32 lanes cover a row; 2 halves x 4 chains
// => 8 edges (4KB) in flight per wave iteration.

__global__ __launch_bounds__(256) void agg_k(const u16* __restrict__ h,
                                             const int* __restrict__ rp,
                                             const int* __restrict__ col,
                                             const float* __restrict__ nd,
                                             const float* __restrict__ bias,
                                             const float* __restrict__ alpha,
                                             const float* __restrict__ ns,
                                             u16* __restrict__ obf, float* __restrict__ of,
                                             int n) {
    int w = (blockIdx.x * blockDim.x + threadIdx.x) >> 6;
    if (w >= n) return;
    const int lane = threadIdx.x & 63;
    const int half = lane >> 5, c0 = (lane & 31) * 8;
    const int beg = rp[w], end = rp[w + 1];

    float a0[8] = {}, a1[8] = {}, a2[8] = {}, a3[8] = {};

    int p = beg + half;  // this half's slots: parity == half
    for (; p + 6 < end; p += 8) {
        int s0 = col[p], s1 = col[p + 2], s2 = col[p + 4], s3 = col[p + 6];
        u16x8 v0 = *(const u16x8*)(h + (size_t)s0 * 256 + c0);
        u16x8 v1 = *(const u16x8*)(h + (size_t)s1 * 256 + c0);
        u16x8 v2 = *(const u16x8*)(h + (size_t)s2 * 256 + c0);
        u16x8 v3 = *(const u16x8*)(h + (size_t)s3 * 256 + c0);
#pragma unroll
        for (int j = 0; j < 8; j++) {
            a0[j] += bf2f(v0[j]);
            a1[j] += bf2f(v1[j]);
            a2[j] += bf2f(v2[j]);
            a3[j] += bf2f(v3[j]);
        }
    }
    for (; p < end; p += 2) {
        int s = col[p];
        u16x8 v = *(const u16x8*)(h + (size_t)s * 256 + c0);
#pragma unroll
        for (int j = 0; j < 8; j++) a0[j] += bf2f(v[j]);
    }
#pragma unroll
    for (int j = 0; j < 8; j++) a0[j] += (a1[j] + a2[j]) + a3[j];
    // combine the two half-wave partial sums (channels identical across halves)
#pragma unroll
    for (int j = 0; j < 8; j++) a0[j] += __shfl_xor(a0[j], 32);

    const float ndv = nd[w];
    const f32x4 bv0 = *(const f32x4*)(bias + c0);
    const f32x4 bv1 = *(const f32x4*)(bias + c0 + 4);
    const f32x4 al0 = *(const f32x4*)(alpha + c0);
    const f32x4 al1 = *(const f32x4*)(alpha + c0 + 4);
    float bb[8] = {bv0[0], bv0[1], bv0[2], bv0[3], bv1[0], bv1[1], bv1[2], bv1[3]};
    float aa[8] = {al0[0], al0[1], al0[2], al0[3], al1[0], al1[1], al1[2], al1[3]};
#pragma unroll
    for (int j = 0; j < 8; j++) {
        float s = a0[j] * ndv + bb[j];
        a0[j] = s > 0.f ? s : aa[j] * s;
    }

    if (half == 0) {
        if (obf) {
            const float nsv = ns[w];
            u16x8 o;
#pragma unroll
            for (int j = 0; j < 8; j++) o[j] = f2bf(a0[j] * nsv);
            *(u16x8*)(obf + (size_t)w * 256 + c0) = o;
        } else {
            f32x4 o0, o1;
            o0[0] = a0[0]; o0[1] = a0[1]; o0[2] = a0[2]; o0[3] = a0[3];
            o1[0] = a0[4]; o1[1] = a0[5]; o1[2] = a0[6]; o1[3] = a0[7];
            *(f32x4*)(of + (size_t)w * 256 + c0) = o0;
            *(f32x4*)(of + (size_t)w * 256 + c0 + 4) = o1;
        }
    }
}

// ---------------- launch ----------------

extern "C" void kernel_launch(void* const* d_in, const int* in_sizes, int n_in,
                              void* d_out, int out_size, void* d_ws, size_t ws_size,
                              hipStream_t stream) {
    const float* feat = (const float*)d_in[0];
    const int* src = (const int*)d_in[1];
    const int* dst = (const int*)d_in[2];
    const float* W1 = (const float*)d_in[3];
    const float* b1 = (const float*)d_in[4];
    const float* a1 = (const float*)d_in[5];
    const float* W2 = (const float*)d_in[6];
    const float* b2 = (const float*)d_in[7];
    const float* a2 = (const float*)d_in[8];
    float* out = (float*)d_out;

    const int N = in_sizes[0] / 512;  // 100000
    const int E = in_sizes[1];        // 3200000
    const int NB = (N + (1 << BSHIFT) - 1) >> BSHIFT;  // 98

    char* ws = (char*)d_ws;
    size_t off = 0;
    auto take = [&](size_t bytes) {
        size_t o = off;
        off += (bytes + 255) & ~(size_t)255;
        return o;
    };
    int* deg_out = (int*)(ws + take((size_t)N * 4));
    int* deg_in = (int*)(ws + take((size_t)N * 4));
    float* nsrc = (float*)(ws + take((size_t)N * 4));
    float* ndst = (float*)(ws + take((size_t)N * 4));
    int* row_ptr = (int*)(ws + take((size_t)(N + 1) * 4));
    int* row_cur = (int*)(ws + take((size_t)N * 4));
    int* sums = (int*)(ws + take(1024));
    int* offs = (int*)(ws + take(1024));
    int* bcur = (int*)(ws + take((size_t)NB * 4));
    int* col = (int*)(ws + take((size_t)E * 4));
    u16* W1t = (u16*)(ws + take((size_t)512 * 256 * 2));
    u16* W2t = (u16*)(ws + take((size_t)256 * 256 * 2));
    u16* h = (u16*)(ws + take((size_t)N * 256 * 2));
    u16* x2 = (u16*)(ws + take((size_t)N * 256 * 2));
    int2* pairs = (int2*)h;  // alias: pairs dead before gemm1 writes h (needs E*8 <= N*512B: 25.6MB <= 51.2MB ok)

    hipMemsetAsync(deg_out, 0, (size_t)N * 4, stream);
    hipMemsetAsync(deg_in, 0, (size_t)N * 4, stream);

    count_k<<<(E + 255) / 256, 256, 0, stream>>>(src, dst, deg_out, deg_in, E);
    norms_k<<<(N + 255) / 256, 256, 0, stream>>>(deg_out, deg_in, nsrc, ndst, N);

    int nb = (N + 511) / 512;  // 196
    scan1_k<<<nb, 512, 0, stream>>>(deg_in, row_ptr, sums, N);
    scan2_k<<<1, 256, 0, stream>>>(sums, offs, nb);
    scan3_k<<<(N + 1 + 255) / 256, 256, 0, stream>>>(row_ptr, offs, row_cur, N, E);

    // bucketed CSR fill
    bcur_init_k<<<(NB + 255) / 256, 256, 0, stream>>>(row_ptr, bcur, NB, N);
    const int chunk = 4096;
    partition_k<<<(E + chunk - 1) / chunk, 256, 0, stream>>>(src, dst, bcur, pairs, E, NB, chunk);
    fill2_k<<<(E + 255) / 256, 256, 0, stream>>>(pairs, row_cur, col, E);

    convt_k<<<(512 * 256 + 255) / 256, 256, 0, stream>>>(W1, W1t, 512, 256);
    convt_k<<<(256 * 256 + 255) / 256, 256, 0, stream>>>(W2, W2t, 256, 256);

    dim3 gg((N + 127) / 128, 2);
    int aggBlocks = (N * 64 + 255) / 256;

    // layer 1
    gemm_k<512, true><<<gg, 256, 0, stream>>>(feat, nsrc, W1t, h, N);
    agg_k<<<aggBlocks, 256, 0, stream>>>(h, row_ptr, col, ndst, b1, a1, nsrc, x2, nullptr, N);
    // layer 2
    gemm_k<256, false><<<gg, 256, 0, stream>>>(x2, nullptr, W2t, h, N);
    agg_k<<<aggBlocks, 256, 0, stream>>>(h, row_ptr, col, ndst, b2, a2, nullptr, nullptr, out, N);
}

// Round 4
// 759.334 us; speedup vs baseline: 1.6966x; 1.2587x over previous
//
#include <hip/hip_runtime.h>
#include <hip/hip_bf16.h>

typedef unsigned short u16;
typedef short s16x8 __attribute__((ext_vector_type(8)));
typedef u16 u16x4 __attribute__((ext_vector_type(4)));
typedef u16 u16x8 __attribute__((ext_vector_type(8)));
typedef float f32x4 __attribute__((ext_vector_type(4)));

#define BSHIFT 10  // bucket = node >> 10 (1024 nodes per bucket)

__device__ __forceinline__ u16 f2bf(float f) {
    __hip_bfloat16 b = __float2bfloat16(f);
    return __builtin_bit_cast(u16, b);
}
__device__ __forceinline__ float bf2f(u16 u) {
    unsigned int x = ((unsigned int)u) << 16;
    return __builtin_bit_cast(float, x);
}

// ---------------- bucket histogram (coarse, both src and dst) ----------------

__global__ __launch_bounds__(256) void bhist_k(const int* __restrict__ src,
                                               const int* __restrict__ dst,
                                               int* __restrict__ bcntA,  // dst buckets
                                               int* __restrict__ bcntB,  // src buckets
                                               int E, int chunk) {
    __shared__ int hA[128], hB[128];
    const int base = blockIdx.x * chunk;
    const int end = (base + chunk) < E ? (base + chunk) : E;
    if (threadIdx.x < 128) { hA[threadIdx.x] = 0; hB[threadIdx.x] = 0; }
    __syncthreads();
    for (int i = base + threadIdx.x; i < end; i += 256) {
        atomicAdd(&hA[dst[i] >> BSHIFT], 1);
        atomicAdd(&hB[src[i] >> BSHIFT], 1);
    }
    __syncthreads();
    if (threadIdx.x < 128) {
        if (hA[threadIdx.x]) atomicAdd(&bcntA[threadIdx.x], hA[threadIdx.x]);
        if (hB[threadIdx.x]) atomicAdd(&bcntB[threadIdx.x], hB[threadIdx.x]);
    }
}

// single block: scan both bucket-count arrays -> bases, init cursors
__global__ void bscan_k(const int* __restrict__ bcntA, const int* __restrict__ bcntB,
                        int* __restrict__ bbaseA, int* __restrict__ bbaseB,
                        int* __restrict__ bcurA, int* __restrict__ bcurB,
                        int* __restrict__ row_ptr, int NB, int N, int E) {
    __shared__ int tA[128], tB[128];
    const int t = threadIdx.x;
    int vA = (t < NB) ? bcntA[t] : 0;
    int vB = (t < NB) ? bcntB[t] : 0;
    tA[t] = vA; tB[t] = vB;
    __syncthreads();
    for (int d = 1; d < 128; d <<= 1) {
        int aA = (t >= d) ? tA[t - d] : 0;
        int aB = (t >= d) ? tB[t - d] : 0;
        __syncthreads();
        tA[t] += aA; tB[t] += aB;
        __syncthreads();
    }
    if (t < NB) {
        int eA = tA[t] - vA, eB = tB[t] - vB;
        bbaseA[t] = eA; bcurA[t] = eA;
        bbaseB[t] = eB; bcurB[t] = eB;
    } else if (t == NB) {
        bbaseA[NB] = E; bbaseB[NB] = E;
    }
    if (t == 0) row_ptr[N] = E;
}

// partition: scatter (src,dst) pairs by dst-bucket AND src values by src-bucket
__global__ __launch_bounds__(256) void part_k(const int* __restrict__ src,
                                              const int* __restrict__ dst,
                                              int* __restrict__ bcurA,
                                              int* __restrict__ bcurB,
                                              int2* __restrict__ pairs,
                                              int* __restrict__ sb,
                                              int E, int chunk) {
    __shared__ int hA[128], hB[128];
    const int base = blockIdx.x * chunk;
    const int end = (base + chunk) < E ? (base + chunk) : E;
    if (threadIdx.x < 128) { hA[threadIdx.x] = 0; hB[threadIdx.x] = 0; }
    __syncthreads();
    for (int i = base + threadIdx.x; i < end; i += 256) {
        atomicAdd(&hA[dst[i] >> BSHIFT], 1);
        atomicAdd(&hB[src[i] >> BSHIFT], 1);
    }
    __syncthreads();
    if (threadIdx.x < 128) {
        int c = hA[threadIdx.x];
        hA[threadIdx.x] = c ? atomicAdd(&bcurA[threadIdx.x], c) : 0;
        c = hB[threadIdx.x];
        hB[threadIdx.x] = c ? atomicAdd(&bcurB[threadIdx.x], c) : 0;
    }
    __syncthreads();
    for (int i = base + threadIdx.x; i < end; i += 256) {
        int d = dst[i], s = src[i];
        int posA = atomicAdd(&hA[d >> BSHIFT], 1);
        int2 pr; pr.x = s; pr.y = d;
        pairs[posA] = pr;
        int posB = atomicAdd(&hB[s >> BSHIFT], 1);
        sb[posB] = s;
    }
}

// per dst-bucket: LDS histogram -> deg_in + row_ptr (dense), then CSR col scatter
__global__ __launch_bounds__(256) void bcsr_k(const int2* __restrict__ pairs,
                                              const int* __restrict__ bbase,
                                              int* __restrict__ row_ptr,
                                              int* __restrict__ din,
                                              int* __restrict__ col, int N) {
    __shared__ int hist[1024];
    __shared__ int cur[1024];
    __shared__ int psum[256];
    const int b = blockIdx.x;
    const int beg = bbase[b], end = bbase[b + 1];
    const int nbase = b << BSHIFT;
    const int nlen = (N - nbase) < 1024 ? (N - nbase) : 1024;
    const int t = threadIdx.x;
#pragma unroll
    for (int j = 0; j < 4; j++) hist[t * 4 + j] = 0;
    __syncthreads();
    for (int i = beg + t; i < end; i += 256)
        atomicAdd(&hist[pairs[i].y - nbase], 1);
    __syncthreads();
    int h0 = hist[4 * t], h1 = hist[4 * t + 1], h2 = hist[4 * t + 2], h3 = hist[4 * t + 3];
    int s = h0 + h1 + h2 + h3;
    psum[t] = s;
    __syncthreads();
    for (int d = 1; d < 256; d <<= 1) {
        int add = (t >= d) ? psum[t - d] : 0;
        __syncthreads();
        psum[t] += add;
        __syncthreads();
    }
    int e0 = psum[t] - s;
    int e1 = e0 + h0, e2 = e1 + h1, e3 = e2 + h2;
    cur[4 * t] = beg + e0; cur[4 * t + 1] = beg + e1;
    cur[4 * t + 2] = beg + e2; cur[4 * t + 3] = beg + e3;
    if (4 * t + 0 < nlen) { row_ptr[nbase + 4 * t + 0] = beg + e0; din[nbase + 4 * t + 0] = h0; }
    if (4 * t + 1 < nlen) { row_ptr[nbase + 4 * t + 1] = beg + e1; din[nbase + 4 * t + 1] = h1; }
    if (4 * t + 2 < nlen) { row_ptr[nbase + 4 * t + 2] = beg + e2; din[nbase + 4 * t + 2] = h2; }
    if (4 * t + 3 < nlen) { row_ptr[nbase + 4 * t + 3] = beg + e3; din[nbase + 4 * t + 3] = h3; }
    __syncthreads();
    for (int i = beg + t; i < end; i += 256) {
        int2 p = pairs[i];
        int pos = atomicAdd(&cur[p.y - nbase], 1);
        col[pos] = p.x;
    }
}

// per src-bucket: LDS histogram -> deg_out (dense)
__global__ __launch_bounds__(256) void bdeg_k(const int* __restrict__ sb,
                                              const int* __restrict__ bbase,
                                              int* __restrict__ dout, int N) {
    __shared__ int hist[1024];
    const int b = blockIdx.x;
    const int beg = bbase[b], end = bbase[b + 1];
    const int nbase = b << BSHIFT;
    const int nlen = (N - nbase) < 1024 ? (N - nbase) : 1024;
    for (int i = threadIdx.x; i < 1024; i += 256) hist[i] = 0;
    __syncthreads();
    for (int i = beg + threadIdx.x; i < end; i += 256)
        atomicAdd(&hist[sb[i] - nbase], 1);
    __syncthreads();
    for (int i = threadIdx.x; i < nlen; i += 256) dout[nbase + i] = hist[i];
}

__global__ void norms_k(const int* __restrict__ dout, const int* __restrict__ din,
                        float* __restrict__ ns, float* __restrict__ nd, int n) {
    int i = blockIdx.x * blockDim.x + threadIdx.x;
    if (i < n) {
        ns[i] = 1.0f / sqrtf(fmaxf((float)dout[i], 1.0f));
        nd[i] = 1.0f / sqrtf(fmaxf((float)din[i], 1.0f));
    }
}

// transpose-convert W[k][n] (f32) -> Wt[n][k] (bf16)
__global__ void convt_k(const float* __restrict__ W, u16* __restrict__ Wt, int K, int Nn) {
    int i = blockIdx.x * blockDim.x + threadIdx.x;
    if (i < K * Nn) {
        int n = i / K, k = i - n * K;
        Wt[i] = f2bf(W[(size_t)k * Nn + n]);
    }
}

// ---------------- GEMM: C[M][256] = A(scaled,bf16) @ W, tile 128x128x64 ----------------

template <int K, bool AF32>
__global__ __launch_bounds__(256) void gemm_k(const void* __restrict__ Ap,
                                              const float* __restrict__ nsrc,
                                              const u16* __restrict__ Bt,  // [256][K] bf16 (W^T)
                                              u16* __restrict__ C, int M) {
    constexpr int BMt = 128, BKt = 64;
    __shared__ u16 Al[BMt * BKt];
    __shared__ u16 Bl[128 * BKt];
    const int tid = threadIdx.x, lane = tid & 63, wid = tid >> 6;
    const int wr = wid >> 1, wc = wid & 1;
    const int l15 = lane & 15, lhi = lane >> 4;
    const int bm = blockIdx.x * BMt, bn = blockIdx.y * 128;
    f32x4 acc[4][4] = {};

    for (int k0 = 0; k0 < K; k0 += BKt) {
#pragma unroll
        for (int i = 0; i < 4; i++) {
            int G = i * 256 + tid, row = G >> 3, gk = G & 7;
            int grow = bm + row;
            grow = grow < M ? grow : M - 1;
            u16x8 w;
            if constexpr (AF32) {
                const float* A = (const float*)Ap;
                const f32x4 v0 = *(const f32x4*)(A + (size_t)grow * K + k0 + gk * 8);
                const f32x4 v1 = *(const f32x4*)(A + (size_t)grow * K + k0 + gk * 8 + 4);
                const float ns = nsrc[grow];
                w[0] = f2bf(v0[0] * ns); w[1] = f2bf(v0[1] * ns);
                w[2] = f2bf(v0[2] * ns); w[3] = f2bf(v0[3] * ns);
                w[4] = f2bf(v1[0] * ns); w[5] = f2bf(v1[1] * ns);
                w[6] = f2bf(v1[2] * ns); w[7] = f2bf(v1[3] * ns);
            } else {
                const u16* A = (const u16*)Ap;
                w = *(const u16x8*)(A + (size_t)grow * K + k0 + gk * 8);
            }
            int idx = (row * BKt + gk * 8) ^ ((row & 7) << 3);  // XOR swizzle, 16B granules
            *(u16x8*)(Al + idx) = w;
            u16x8 wb = *(const u16x8*)(Bt + (size_t)(bn + row) * K + k0 + gk * 8);
            *(u16x8*)(Bl + idx) = wb;
        }
        __syncthreads();

        s16x8 af[2][4], bfr[2][4];
#pragma unroll
        for (int kk = 0; kk < 2; kk++) {
#pragma unroll
            for (int mi = 0; mi < 4; mi++) {
                int row = wr * 64 + mi * 16 + l15;
                int idx = (row * BKt + kk * 32 + lhi * 8) ^ ((row & 7) << 3);
                af[kk][mi] = *(const s16x8*)(Al + idx);
            }
#pragma unroll
            for (int ni = 0; ni < 4; ni++) {
                int n = wc * 64 + ni * 16 + l15;
                int idx = (n * BKt + kk * 32 + lhi * 8) ^ ((n & 7) << 3);
                bfr[kk][ni] = *(const s16x8*)(Bl + idx);
            }
        }
#pragma unroll
        for (int kk = 0; kk < 2; kk++)
#pragma unroll
            for (int mi = 0; mi < 4; mi++)
#pragma unroll
                for (int ni = 0; ni < 4; ni++)
                    acc[mi][ni] = __builtin_amdgcn_mfma_f32_16x16x32_bf16(
                        af[kk][mi], bfr[kk][ni], acc[mi][ni], 0, 0, 0);
        __syncthreads();
    }

    // epilogue: C/D layout col=lane&15, row=(lane>>4)*4+reg
#pragma unroll
    for (int mi = 0; mi < 4; mi++) {
#pragma unroll
        for (int r = 0; r < 4; r++) {
            int grow = bm + wr * 64 + mi * 16 + lhi * 4 + r;
            if (grow < M) {
#pragma unroll
                for (int ni = 0; ni < 4; ni++) {
                    int gcol = bn + wc * 64 + ni * 16 + l15;
                    C[(size_t)grow * 256 + gcol] = f2bf(acc[mi][ni][r]);
                }
            }
        }
    }
}

// ---------------- pull aggregation + epilogue ----------------
// One wave per dst node. 16B/lane, 32 lanes cover a row; 2 halves x 4 chains
// => 8 edges (4KB) in flight per wave iteration.

__global__ __launch_bounds__(256) void agg_k(const u16* __restrict__ h,
                                             const int* __restrict__ rp,
                                             const int* __restrict__ col,
                                             const float* __restrict__ nd,
                                             const float* __restrict__ bias,
                                             const float* __restrict__ alpha,
                                             const float* __restrict__ ns,
                                             u16* __restrict__ obf, float* __restrict__ of,
                                             int n) {
    int w = (blockIdx.x * blockDim.x + threadIdx.x) >> 6;
    if (w >= n) return;
    const int lane = threadIdx.x & 63;
    const int half = lane >> 5, c0 = (lane & 31) * 8;
    const int beg = rp[w], end = rp[w + 1];

    float a0[8] = {}, a1[8] = {}, a2[8] = {}, a3[8] = {};

    int p = beg + half;  // this half's slots: parity == half
    for (; p + 6 < end; p += 8) {
        int s0 = col[p], s1 = col[p + 2], s2 = col[p + 4], s3 = col[p + 6];
        u16x8 v0 = *(const u16x8*)(h + (size_t)s0 * 256 + c0);
        u16x8 v1 = *(const u16x8*)(h + (size_t)s1 * 256 + c0);
        u16x8 v2 = *(const u16x8*)(h + (size_t)s2 * 256 + c0);
        u16x8 v3 = *(const u16x8*)(h + (size_t)s3 * 256 + c0);
#pragma unroll
        for (int j = 0; j < 8; j++) {
            a0[j] += bf2f(v0[j]);
            a1[j] += bf2f(v1[j]);
            a2[j] += bf2f(v2[j]);
            a3[j] += bf2f(v3[j]);
        }
    }
    for (; p < end; p += 2) {
        int s = col[p];
        u16x8 v = *(const u16x8*)(h + (size_t)s * 256 + c0);
#pragma unroll
        for (int j = 0; j < 8; j++) a0[j] += bf2f(v[j]);
    }
#pragma unroll
    for (int j = 0; j < 8; j++) a0[j] += (a1[j] + a2[j]) + a3[j];
    // combine the two half-wave partial sums (channels identical across halves)
#pragma unroll
    for (int j = 0; j < 8; j++) a0[j] += __shfl_xor(a0[j], 32);

    const float ndv = nd[w];
    const f32x4 bv0 = *(const f32x4*)(bias + c0);
    const f32x4 bv1 = *(const f32x4*)(bias + c0 + 4);
    const f32x4 al0 = *(const f32x4*)(alpha + c0);
    const f32x4 al1 = *(const f32x4*)(alpha + c0 + 4);
    float bb[8] = {bv0[0], bv0[1], bv0[2], bv0[3], bv1[0], bv1[1], bv1[2], bv1[3]};
    float aa[8] = {al0[0], al0[1], al0[2], al0[3], al1[0], al1[1], al1[2], al1[3]};
#pragma unroll
    for (int j = 0; j < 8; j++) {
        float s = a0[j] * ndv + bb[j];
        a0[j] = s > 0.f ? s : aa[j] * s;
    }

    if (half == 0) {
        if (obf) {
            const float nsv = ns[w];
            u16x8 o;
#pragma unroll
            for (int j = 0; j < 8; j++) o[j] = f2bf(a0[j] * nsv);
            *(u16x8*)(obf + (size_t)w * 256 + c0) = o;
        } else {
            f32x4 o0, o1;
            o0[0] = a0[0]; o0[1] = a0[1]; o0[2] = a0[2]; o0[3] = a0[3];
            o1[0] = a0[4]; o1[1] = a0[5]; o1[2] = a0[6]; o1[3] = a0[7];
            *(f32x4*)(of + (size_t)w * 256 + c0) = o0;
            *(f32x4*)(of + (size_t)w * 256 + c0 + 4) = o1;
        }
    }
}

// ---------------- launch ----------------

extern "C" void kernel_launch(void* const* d_in, const int* in_sizes, int n_in,
                              void* d_out, int out_size, void* d_ws, size_t ws_size,
                              hipStream_t stream) {
    const float* feat = (const float*)d_in[0];
    const int* src = (const int*)d_in[1];
    const int* dst = (const int*)d_in[2];
    const float* W1 = (const float*)d_in[3];
    const float* b1 = (const float*)d_in[4];
    const float* a1 = (const float*)d_in[5];
    const float* W2 = (const float*)d_in[6];
    const float* b2 = (const float*)d_in[7];
    const float* a2 = (const float*)d_in[8];
    float* out = (float*)d_out;

    const int N = in_sizes[0] / 512;  // 100000
    const int E = in_sizes[1];        // 3200000
    const int NB = (N + (1 << BSHIFT) - 1) >> BSHIFT;  // 98

    char* ws = (char*)d_ws;
    size_t off = 0;
    auto take = [&](size_t bytes) {
        size_t o = off;
        off += (bytes + 255) & ~(size_t)255;
        return o;
    };
    int* deg_out = (int*)(ws + take((size_t)N * 4));
    int* deg_in = (int*)(ws + take((size_t)N * 4));
    float* nsrc = (float*)(ws + take((size_t)N * 4));
    float* ndst = (float*)(ws + take((size_t)N * 4));
    int* row_ptr = (int*)(ws + take((size_t)(N + 1) * 4));
    int* bcnt = (int*)(ws + take(1024));  // bcntA[128] + bcntB[128]
    int* bcntA = bcnt, * bcntB = bcnt + 128;
    int* bbaseA = (int*)(ws + take(512));
    int* bbaseB = (int*)(ws + take(512));
    int* bcurA = (int*)(ws + take(512));
    int* bcurB = (int*)(ws + take(512));
    int* col = (int*)(ws + take((size_t)E * 4));
    u16* W1t = (u16*)(ws + take((size_t)512 * 256 * 2));
    u16* W2t = (u16*)(ws + take((size_t)256 * 256 * 2));
    u16* h = (u16*)(ws + take((size_t)N * 256 * 2));
    u16* x2 = (u16*)(ws + take((size_t)N * 256 * 2));
    int2* pairs = (int2*)h;  // alias: dead before gemm1 writes h (25.6MB <= 51.2MB)
    int* sb = (int*)x2;      // alias: dead before agg1 writes x2 (12.8MB <= 51.2MB)

    hipMemsetAsync(bcnt, 0, 1024, stream);

    const int chunk = 4096;
    bhist_k<<<(E + chunk - 1) / chunk, 256, 0, stream>>>(src, dst, bcntA, bcntB, E, chunk);
    bscan_k<<<1, 128, 0, stream>>>(bcntA, bcntB, bbaseA, bbaseB, bcurA, bcurB, row_ptr, NB, N, E);
    part_k<<<(E + chunk - 1) / chunk, 256, 0, stream>>>(src, dst, bcurA, bcurB, pairs, sb, E, chunk);
    bcsr_k<<<NB, 256, 0, stream>>>(pairs, bbaseA, row_ptr, deg_in, col, N);
    bdeg_k<<<NB, 256, 0, stream>>>(sb, bbaseB, deg_out, N);
    norms_k<<<(N + 255) / 256, 256, 0, stream>>>(deg_out, deg_in, nsrc, ndst, N);

    convt_k<<<(512 * 256 + 255) / 256, 256, 0, stream>>>(W1, W1t, 512, 256);
    convt_k<<<(256 * 256 + 255) / 256, 256, 0, stream>>>(W2, W2t, 256, 256);

    dim3 gg((N + 127) / 128, 2);
    int aggBlocks = (N * 64 + 255) / 256;

    // layer 1
    gemm_k<512, true><<<gg, 256, 0, stream>>>(feat, nsrc, W1t, h, N);
    agg_k<<<aggBlocks, 256, 0, stream>>>(h, row_ptr, col, ndst, b1, a1, nsrc, x2, nullptr, N);
    // layer 2
    gemm_k<256, false><<<gg, 256, 0, stream>>>(x2, nullptr, W2t, h, N);
    agg_k<<<aggBlocks, 256, 0, stream>>>(h, row_ptr, col, ndst, b2, a2, nullptr, nullptr, out, N);
}